// Round 5
// baseline (224.913 us; speedup 1.0000x reference)
//
#include <hip/hip_runtime.h>

// GAT layer on MI355X. N=50000, E=800000 (+N self loops), DIN=256, DOUT=128, H=8.
//
//  K1 conv_w       : W_bf = bf16(W_trans); zeroes per-bucket counters
//  K2 gemm_ns      : h_bf = bf16(x @ W^T) via 16x16x32 bf16 MFMA, x staged in LDS
//                    (coalesced float4), + fused per-node attention half-scores
//  K3 bucket_pass  : edges -> per-256-node-bucket regions (atomic-cursor runs,
//                    packed u32 = src<<8 | dst&255); bcount[b] = bucket size
//  K4 fine_scatter : 2 blocks per bucket (128 nodes each): per-(node, src-range)
//                    LDS hist + scan -> offsets[], len8[], self-loop inject,
//                    rank-scatter ushort src ids grouped by 5 src-ranges of 10000
//  K5 aggregate    : one wave per dst node, 4 edges per wave-instr (16 lanes x
//                    uint4); iterates the 5 src-ranges in order so concurrent
//                    waves gather from an L2-resident 2.56 MB hbf window

constexpr int DIN  = 256;
constexpr int DOUT = 128;
constexpr int H    = 8;
constexpr int CAP  = 5120;   // pair_buf slots per bucket (mean 4096, +16 sigma)
constexpr int NRANGE = 5;    // src ranges of 10000 nodes (2.56 MB of hbf each)

typedef __attribute__((ext_vector_type(8))) short bf16x8;
typedef __attribute__((ext_vector_type(4))) float f32x4;

__device__ __forceinline__ float lrelu(float s) { return s >= 0.0f ? s : 0.2f * s; }

__device__ __forceinline__ unsigned short f2bf(float f) {  // RNE
  unsigned u = __float_as_uint(f);
  u += 0x7FFF + ((u >> 16) & 1);
  return (unsigned short)(u >> 16);
}
__device__ __forceinline__ float bflo(unsigned u) { return __uint_as_float(u << 16); }
__device__ __forceinline__ float bfhi(unsigned u) { return __uint_as_float(u & 0xFFFF0000u); }
__device__ __forceinline__ int rng5(int s) {  // s/10000 for s < 50000
  return (int)__umulhi((unsigned)s, 429497u);
}

__device__ __forceinline__ int wave_incl_scan(int v, int lane) {
#pragma unroll
  for (int d = 1; d < 64; d <<= 1) {
    int t = __shfl_up(v, d, 64);
    if (lane >= d) v += t;
  }
  return v;
}

__device__ __forceinline__ float red16(float v) {  // sum over 16-lane group
  v += __shfl_xor(v, 1, 64);
  v += __shfl_xor(v, 2, 64);
  v += __shfl_xor(v, 4, 64);
  v += __shfl_xor(v, 8, 64);
  return v;
}

// ---------------- K1: W -> bf16 (+ zero bucket counters) ----------------
__global__ void conv_w(const float* __restrict__ W, unsigned short* __restrict__ Wbf,
                       int n, int* __restrict__ bcount, int nb) {
  int i = blockIdx.x * blockDim.x + threadIdx.x;
  if (i < n) Wbf[i] = f2bf(W[i]);
  if (blockIdx.x == 0 && threadIdx.x < nb) bcount[threadIdx.x] = 0;
}

// ---------------- K2: GEMM (LDS-staged x) + fused node scores ----------------
// Block: 64 rows. Stage x (64x256 fp32) coalesced -> bf16 LDS (row stride 264).
// Wave w: rows w*16..w*16+15. A-frag lane(mr,kg): xs[w*16+mr][ks*32+kg*8..+8).
// C/D: col = lane&15 (=mr), row = kg*4 + reg.
__global__ __launch_bounds__(256) void gemm_ns(const float* __restrict__ x,
                                               const unsigned short* __restrict__ Wbf,
                                               const float* __restrict__ Wa,
                                               unsigned short* __restrict__ hbf,
                                               float* __restrict__ a_src,
                                               float* __restrict__ a_dst, int N) {
  __shared__ __align__(16) unsigned short xs[64][264];
  const int tid = threadIdx.x;
  const int rb = blockIdx.x * 64;
  const float* xb = x + (size_t)rb * DIN;
  int maxf = (N - rb) * 64;  // valid float4 count in this tile
#pragma unroll
  for (int i = 0; i < 16; ++i) {
    int f = i * 256 + tid;
    int row = f >> 6, c4 = (f & 63) * 4;
    float4 v = make_float4(0.f, 0.f, 0.f, 0.f);
    if (f < maxf) v = *(const float4*)(xb + (size_t)f * 4);
    ushort4 wv;
    wv.x = f2bf(v.x); wv.y = f2bf(v.y); wv.z = f2bf(v.z); wv.w = f2bf(v.w);
    *(ushort4*)&xs[row][c4] = wv;
  }
  __syncthreads();

  const int w = tid >> 6, lane = tid & 63;
  const int mr = lane & 15, kg = lane >> 4;

  f32x4 acc[8];
#pragma unroll
  for (int t = 0; t < 8; ++t) acc[t] = (f32x4){0.f, 0.f, 0.f, 0.f};

#pragma unroll
  for (int ks = 0; ks < 8; ++ks) {
    bf16x8 a = *(const bf16x8*)&xs[w * 16 + mr][ks * 32 + kg * 8];
#pragma unroll
    for (int t = 0; t < 8; ++t) {
      bf16x8 b = *(const bf16x8*)(Wbf + (t * 16 + mr) * DIN + ks * 32 + kg * 8);
      acc[t] = __builtin_amdgcn_mfma_f32_16x16x32_bf16(a, b, acc[t], 0, 0, 0);
    }
  }

  // epilogue: store bf16 h + fused attention half-scores
  float wa1 = Wa[mr];       // src half of W_att
  float wa2 = Wa[16 + mr];  // dst half
  float keep1[4] = {0, 0, 0, 0}, keep2[4] = {0, 0, 0, 0};
#pragma unroll
  for (int t = 0; t < 8; ++t) {
#pragma unroll
    for (int r = 0; r < 4; ++r) {
      int row = rb + w * 16 + kg * 4 + r;
      unsigned short us = f2bf(acc[t][r]);
      if (row < N) hbf[row * DOUT + t * 16 + mr] = us;
      float hv = __uint_as_float(((unsigned)us) << 16);
      float r1 = red16(hv * wa1);
      float r2 = red16(hv * wa2);
      if (mr == t) keep1[r] = r1;
      if (mr == t + 8) keep2[r] = r2;
    }
  }
#pragma unroll
  for (int r = 0; r < 4; ++r) {
    int row = rb + w * 16 + kg * 4 + r;
    if (row < N) {
      if (mr < 8) a_src[row * H + mr] = keep1[r];
      else        a_dst[row * H + (mr - 8)] = keep2[r];
    }
  }
}

// ---------------- K3: partition edges into bucket regions ----------------
constexpr int CHUNK = 4096;  // 16 edges per thread
__global__ __launch_bounds__(256) void bucket_pass(const int* __restrict__ ei,
                                                   int* __restrict__ bcount,
                                                   unsigned* __restrict__ pair_buf,
                                                   int E, int nb) {
  __shared__ int hist[256];
  __shared__ int gbase[256];
  int c0 = blockIdx.x * CHUNK;
  hist[threadIdx.x] = 0;
  __syncthreads();
  int dcache[16];
#pragma unroll
  for (int q = 0; q < 16; ++q) {
    int e = c0 + q * 256 + threadIdx.x;
    dcache[q] = (e < E) ? ei[E + e] : -1;
    if (dcache[q] >= 0) atomicAdd(&hist[dcache[q] >> 8], 1);
  }
  __syncthreads();
  if (threadIdx.x < nb) {
    int c = hist[threadIdx.x];
    gbase[threadIdx.x] = c ? atomicAdd(&bcount[threadIdx.x], c) : 0;
  }
  __syncthreads();
  hist[threadIdx.x] = 0;  // reuse as local rank cursor
  __syncthreads();
#pragma unroll
  for (int q = 0; q < 16; ++q) {
    int e = c0 + q * 256 + threadIdx.x;
    if (dcache[q] >= 0) {
      int s = ei[e];
      int bk = dcache[q] >> 8;
      int r = atomicAdd(&hist[bk], 1);
      pair_buf[bk * CAP + gbase[bk] + r] = ((unsigned)s << 8) | (unsigned)(dcache[q] & 255);
    }
  }
}

// ---------------- K4: per-half-bucket fine scatter, range-ordered CSR ----------------
__global__ __launch_bounds__(256) void fine_scatter(const unsigned* __restrict__ pair_buf,
                                                    const int* __restrict__ bcount,
                                                    int* __restrict__ offsets,
                                                    uint4* __restrict__ len8,
                                                    unsigned short* __restrict__ src_sorted,
                                                    int N, int E, int nb) {
  __shared__ int cnt[128 * NRANGE];
  __shared__ int cur[128 * NRANGE];
  __shared__ int redS[256];
  __shared__ int wsumS[4];
  __shared__ int lowerE;
  const int b = blockIdx.x, t = threadIdx.x;
  const int B = b >> 1, half = b & 1;
  const int node0 = b * 128;
  if (node0 >= N) return;
  for (int i = t; i < 128 * NRANGE; i += 256) cnt[i] = 0;
  if (t == 0) lowerE = 0;
  __syncthreads();
  const int v = node0 + t;
  int r_self = -1;
  if (t < 128 && v < N) {
    r_self = rng5(v);
    cnt[t * NRANGE + r_self] = 1;  // self loop
  }
  __syncthreads();
  const int cntE = bcount[B];
  const unsigned* reg = pair_buf + B * CAP;
  for (int i = t; i < cntE; i += 256) {
    unsigned p = reg[i];
    int dl = p & 255;
    if ((dl >> 7) == half) atomicAdd(&cnt[(dl & 127) * NRANGE + rng5((int)(p >> 8))], 1);
    else if (half == 1) atomicAdd(&lowerE, 1);
  }
  // bucket edge base = sum of earlier bucket counts
  redS[t] = (t < B) ? bcount[t] : 0;
  __syncthreads();
  for (int s = 128; s > 0; s >>= 1) {
    if (t < s) redS[t] += redS[t + s];
    __syncthreads();
  }
  int csr_base = redS[0] + B * 256 + (half ? (128 + lowerE) : 0);
  // per-node totals + block scan
  int tot = 0;
  if (t < 128) {
#pragma unroll
    for (int r = 0; r < NRANGE; ++r) tot += cnt[t * NRANGE + r];
  }
  int lane = t & 63, wv = t >> 6;
  int inc = wave_incl_scan(tot, lane);
  if (lane == 63) wsumS[wv] = inc;
  __syncthreads();
  int base = 0;
  for (int q = 0; q < wv; ++q) base += wsumS[q];
  int ex = base + inc - tot;
  if (t < 128 && v < N) {
    offsets[v] = csr_base + ex;
    int run = ex, rs_self = 0, c[NRANGE];
#pragma unroll
    for (int r = 0; r < NRANGE; ++r) {
      c[r] = cnt[t * NRANGE + r];
      if (r == r_self) rs_self = run;
      cur[t * NRANGE + r] = run + (r == r_self ? 1 : 0);
      run += c[r];
    }
    src_sorted[csr_base + rs_self] = (unsigned short)v;  // self loop
    uint4 L;
    L.x = (unsigned)c[0] | ((unsigned)c[1] << 16);
    L.y = (unsigned)c[2] | ((unsigned)c[3] << 16);
    L.z = (unsigned)c[4];
    L.w = 0;
    len8[v] = L;
  }
  if (b == 0 && t == 0) offsets[N] = E + N;
  __syncthreads();
  for (int i = t; i < cntE; i += 256) {
    unsigned p = reg[i];
    int dl = p & 255;
    if ((dl >> 7) == half) {
      int s = (int)(p >> 8);
      int k = atomicAdd(&cur[(dl & 127) * NRANGE + rng5(s)], 1);
      src_sorted[csr_base + k] = (unsigned short)s;
    }
  }
}

// ---------------- K5: aggregation, 4 edges / wave-instr, src-range passes ----------------
// One wave per dst node. Group g = lane>>4 handles edge j+g; sub-lane sl = lane&15
// covers cols [sl*8, sl*8+8) (16B uint4 load); head = sl>>1.
__global__ __launch_bounds__(256) void aggregate(const unsigned short* __restrict__ hbf,
                                                 const float* __restrict__ a_src,
                                                 const float* __restrict__ a_dst,
                                                 const float* __restrict__ b_att,
                                                 const int* __restrict__ offsets,
                                                 const uint4* __restrict__ len8,
                                                 const unsigned short* __restrict__ src_sorted,
                                                 float* __restrict__ out, int N) {
  int wid = blockIdx.x * 4 + (threadIdx.x >> 6);
  if (wid >= N) return;
  int lane = threadIdx.x & 63;
  int g = lane >> 4, sl = lane & 15;
  int head = sl >> 1;
  float adv = a_dst[wid * H + head] + b_att[0];
  int j = offsets[wid];
  uint4 L = len8[wid];
  int lens[NRANGE];
  lens[0] = L.x & 0xffff; lens[1] = L.x >> 16;
  lens[2] = L.y & 0xffff; lens[3] = L.y >> 16;
  lens[4] = L.z;
  float a0 = 0, a1 = 0, a2 = 0, a3 = 0, a4 = 0, a5 = 0, a6 = 0, a7 = 0, den = 0;
  for (int r = 0; r < NRANGE; ++r) {
    int end = j + lens[r];
    for (int j0 = j; j0 < end; j0 += 4) {
      int jj = j0 + g;
      bool val = jj < end;
      int jc = val ? jj : end - 1;
      int s = src_sorted[jc];
      float as = a_src[s * H + head];
      uint4 u = *(const uint4*)(hbf + s * DOUT + sl * 8);
      float e = val ? __expf(lrelu(as + adv)) : 0.f;
      den += e;
      a0 += e * bflo(u.x); a1 += e * bfhi(u.x);
      a2 += e * bflo(u.y); a3 += e * bfhi(u.y);
      a4 += e * bflo(u.z); a5 += e * bfhi(u.z);
      a6 += e * bflo(u.w); a7 += e * bfhi(u.w);
    }
    j = end;
  }
  den += __shfl_xor(den, 16, 64); den += __shfl_xor(den, 32, 64);
  a0 += __shfl_xor(a0, 16, 64); a0 += __shfl_xor(a0, 32, 64);
  a1 += __shfl_xor(a1, 16, 64); a1 += __shfl_xor(a1, 32, 64);
  a2 += __shfl_xor(a2, 16, 64); a2 += __shfl_xor(a2, 32, 64);
  a3 += __shfl_xor(a3, 16, 64); a3 += __shfl_xor(a3, 32, 64);
  a4 += __shfl_xor(a4, 16, 64); a4 += __shfl_xor(a4, 32, 64);
  a5 += __shfl_xor(a5, 16, 64); a5 += __shfl_xor(a5, 32, 64);
  a6 += __shfl_xor(a6, 16, 64); a6 += __shfl_xor(a6, 32, 64);
  a7 += __shfl_xor(a7, 16, 64); a7 += __shfl_xor(a7, 32, 64);
  float inv = 1.0f / den;
  if (g == 0) {
    float4 o = make_float4(a0 * inv, a1 * inv, a2 * inv, a3 * inv);
    *(float4*)&out[wid * DOUT + sl * 8] = o;
  } else if (g == 1) {
    float4 o = make_float4(a4 * inv, a5 * inv, a6 * inv, a7 * inv);
    *(float4*)&out[wid * DOUT + sl * 8 + 4] = o;
  }
}

extern "C" void kernel_launch(void* const* d_in, const int* in_sizes, int n_in,
                              void* d_out, int out_size, void* d_ws, size_t ws_size,
                              hipStream_t stream) {
  const float* x     = (const float*)d_in[0];
  const float* W     = (const float*)d_in[1];
  const float* Wa    = (const float*)d_in[2];
  const float* b_att = (const float*)d_in[3];
  const int*   ei    = (const int*)d_in[4];
  const int N  = in_sizes[0] / DIN;
  const int E  = in_sizes[4] / 2;
  const int NB = (N + 255) / 256;  // 196 buckets
  float* out = (float*)d_out;

  char* p = (char*)d_ws;
  auto take = [&p](size_t bytes) {
    uintptr_t u = ((uintptr_t)p + 15) & ~(uintptr_t)15;
    p = (char*)(u + bytes);
    return (void*)u;
  };
  unsigned short* hbf = (unsigned short*)take((size_t)N * DOUT * 2);
  unsigned short* Wbf = (unsigned short*)take((size_t)DOUT * DIN * 2);
  float* a_src        = (float*)take((size_t)N * H * 4);
  float* a_dst        = (float*)take((size_t)N * H * 4);
  int* bcount         = (int*)take((size_t)NB * 4);
  unsigned* pair_buf  = (unsigned*)take((size_t)NB * CAP * 4);
  int* offsets        = (int*)take((size_t)(N + 1) * 4);
  uint4* len8         = (uint4*)take((size_t)N * 16);
  unsigned short* src_sorted = (unsigned short*)take((size_t)(E + N + 16) * 2);

  dim3 b256(256);
  conv_w<<<dim3((DOUT * DIN + 255) / 256), b256, 0, stream>>>(W, Wbf, DOUT * DIN, bcount, NB);
  gemm_ns<<<dim3((N + 63) / 64), b256, 0, stream>>>(x, Wbf, Wa, hbf, a_src, a_dst, N);
  bucket_pass<<<dim3((E + CHUNK - 1) / CHUNK), b256, 0, stream>>>(ei, bcount, pair_buf, E, NB);
  fine_scatter<<<dim3((N + 127) / 128), b256, 0, stream>>>(pair_buf, bcount, offsets, len8,
                                                           src_sorted, N, E, NB);
  aggregate<<<dim3((N + 3) / 4), b256, 0, stream>>>(hbf, a_src, a_dst, b_att, offsets,
                                                    len8, src_sorted, out, N);
}

// Round 6
// 195.392 us; speedup vs baseline: 1.1511x; 1.1511x over previous
//
#include <hip/hip_runtime.h>

// GAT layer on MI355X. N=50000, E=800000 (+N self loops), DIN=256, DOUT=128, H=8.
//
//  K1 conv_w       : W_bf = bf16(W_trans); zeroes per-bucket counters
//  K2 bp_gemm      : [blocks 0..195]   bucket_pass: edges -> per-256-node-bucket
//                    regions (atomic cursors, packed u32 = src<<8 | dst&255)
//                    [blocks 196..]    gemm: h_bf = bf16(x @ W^T), 16x16x32 MFMA,
//                    16 prefetched x-loads/lane, 16 rows x 64 cols per wave
//  K3 fs_ns        : [blocks 0..390]   fine_scatter: per-(node, src-range) LDS
//                    hist+scan -> offsets[], len8[], range-ordered ushort CSR
//                    [blocks 391..]    node_scores: a_src/a_dst from h_bf
//  K4 aggregate    : one wave per dst node, 4 edges per wave-instr (16 lanes x
//                    uint4); iterates 5 src-ranges so concurrent waves gather
//                    from an L2-resident 2.56 MB hbf window

constexpr int DIN  = 256;
constexpr int DOUT = 128;
constexpr int H    = 8;
constexpr int CAP  = 5120;   // pair_buf slots per bucket (mean 4096, +16 sigma)
constexpr int NRANGE = 5;    // src ranges of 10000 nodes (2.56 MB of hbf each)
constexpr int CHUNK = 4096;  // edges per bucket_pass block

typedef __attribute__((ext_vector_type(8))) short bf16x8;
typedef __attribute__((ext_vector_type(4))) float f32x4;

__device__ __forceinline__ float lrelu(float s) { return s >= 0.0f ? s : 0.2f * s; }

__device__ __forceinline__ unsigned short f2bf(float f) {  // RNE
  unsigned u = __float_as_uint(f);
  u += 0x7FFF + ((u >> 16) & 1);
  return (unsigned short)(u >> 16);
}
__device__ __forceinline__ float bflo(unsigned u) { return __uint_as_float(u << 16); }
__device__ __forceinline__ float bfhi(unsigned u) { return __uint_as_float(u & 0xFFFF0000u); }
__device__ __forceinline__ int rng5(int s) {  // s/10000 for s < 50000
  return (int)__umulhi((unsigned)s, 429497u);
}

__device__ __forceinline__ int wave_incl_scan(int v, int lane) {
#pragma unroll
  for (int d = 1; d < 64; d <<= 1) {
    int t = __shfl_up(v, d, 64);
    if (lane >= d) v += t;
  }
  return v;
}

// ---------------- K1: W -> bf16 (+ zero bucket counters) ----------------
__global__ void conv_w(const float* __restrict__ W, unsigned short* __restrict__ Wbf,
                       int n, int* __restrict__ bcount, int nb) {
  int i = blockIdx.x * blockDim.x + threadIdx.x;
  if (i < n) Wbf[i] = f2bf(W[i]);
  if (blockIdx.x == 0 && threadIdx.x < nb) bcount[threadIdx.x] = 0;
}

// ---------------- K2: fused bucket_pass + GEMM ----------------
// gemm wave: 16 rows x 64 cols. A-frag lane(mr,kg) holds A[m0+mr][ks*32+kg*8..+8);
// C/D: col = lane&15, row = kg*4 + reg.
__global__ __launch_bounds__(256) void bp_gemm(const float* __restrict__ x,
                                               const unsigned short* __restrict__ Wbf,
                                               unsigned short* __restrict__ hbf, int N,
                                               const int* __restrict__ ei,
                                               int* __restrict__ bcount,
                                               unsigned* __restrict__ pair_buf,
                                               int E, int nb, int bp_blocks) {
  __shared__ int hist[256];
  __shared__ int gbase[256];
  if ((int)blockIdx.x < bp_blocks) {
    // ---- bucket_pass ----
    int c0 = blockIdx.x * CHUNK;
    hist[threadIdx.x] = 0;
    __syncthreads();
    int dcache[16];
#pragma unroll
    for (int q = 0; q < 16; ++q) {
      int e = c0 + q * 256 + threadIdx.x;
      dcache[q] = (e < E) ? ei[E + e] : -1;
      if (dcache[q] >= 0) atomicAdd(&hist[dcache[q] >> 8], 1);
    }
    __syncthreads();
    if (threadIdx.x < nb) {
      int c = hist[threadIdx.x];
      gbase[threadIdx.x] = c ? atomicAdd(&bcount[threadIdx.x], c) : 0;
    }
    __syncthreads();
    hist[threadIdx.x] = 0;  // reuse as local rank cursor
    __syncthreads();
#pragma unroll
    for (int q = 0; q < 16; ++q) {
      int e = c0 + q * 256 + threadIdx.x;
      if (dcache[q] >= 0) {
        int s = ei[e];
        int bk = dcache[q] >> 8;
        int r = atomicAdd(&hist[bk], 1);
        pair_buf[bk * CAP + gbase[bk] + r] = ((unsigned)s << 8) | (unsigned)(dcache[q] & 255);
      }
    }
    return;
  }
  // ---- GEMM ----
  int gb = blockIdx.x - bp_blocks;
  int tid = threadIdx.x;
  int w = tid >> 6, lane = tid & 63;
  int mr = lane & 15, kg = lane >> 4;
  int m0 = gb * 32 + (w >> 1) * 16;
  int nt0 = (w & 1) * 4;  // first of 4 n-tiles (cols nt0*16 .. nt0*16+63)
  if (m0 >= N) return;
  int rr = m0 + mr;
  if (rr >= N) rr = N - 1;  // clamp (stores are guarded; dup reads harmless)
  const float* xrow = x + (size_t)rr * DIN + kg * 8;

  // prefetch all 16 x-vectors (16 outstanding loads/lane)
  float4 xa[8], xc[8];
#pragma unroll
  for (int ks = 0; ks < 8; ++ks) {
    xa[ks] = *(const float4*)(xrow + ks * 32);
    xc[ks] = *(const float4*)(xrow + ks * 32 + 4);
  }

  f32x4 acc[4];
#pragma unroll
  for (int t = 0; t < 4; ++t) acc[t] = (f32x4){0.f, 0.f, 0.f, 0.f};

#pragma unroll
  for (int ks = 0; ks < 8; ++ks) {
    bf16x8 a;
    a[0] = (short)f2bf(xa[ks].x); a[1] = (short)f2bf(xa[ks].y);
    a[2] = (short)f2bf(xa[ks].z); a[3] = (short)f2bf(xa[ks].w);
    a[4] = (short)f2bf(xc[ks].x); a[5] = (short)f2bf(xc[ks].y);
    a[6] = (short)f2bf(xc[ks].z); a[7] = (short)f2bf(xc[ks].w);
#pragma unroll
    for (int t = 0; t < 4; ++t) {
      bf16x8 b = *(const bf16x8*)(Wbf + ((nt0 + t) * 16 + mr) * DIN + ks * 32 + kg * 8);
      acc[t] = __builtin_amdgcn_mfma_f32_16x16x32_bf16(a, b, acc[t], 0, 0, 0);
    }
  }
#pragma unroll
  for (int t = 0; t < 4; ++t) {
#pragma unroll
    for (int r = 0; r < 4; ++r) {
      int row = m0 + kg * 4 + r;
      if (row < N) hbf[row * DOUT + (nt0 + t) * 16 + mr] = f2bf(acc[t][r]);
    }
  }
}

// ---------------- K3: fused fine_scatter + node_scores ----------------
__global__ __launch_bounds__(256) void fs_ns(const unsigned* __restrict__ pair_buf,
                                             const int* __restrict__ bcount,
                                             int* __restrict__ offsets,
                                             uint4* __restrict__ len8,
                                             unsigned short* __restrict__ src_sorted,
                                             const unsigned short* __restrict__ hbf,
                                             const float* __restrict__ Wa,
                                             float* __restrict__ a_src,
                                             float* __restrict__ a_dst,
                                             int N, int E, int nb, int fs_blocks) {
  __shared__ int cnt[128 * NRANGE];
  __shared__ int cur[128 * NRANGE];
  __shared__ int redS[256];
  __shared__ int wsumS[4];
  __shared__ int lowerE;
  const int t = threadIdx.x;
  if ((int)blockIdx.x >= fs_blocks) {
    // ---- node_scores ----
    int idx = ((int)blockIdx.x - fs_blocks) * 256 + t;
    if (idx >= N * H) return;
    int v = idx >> 3, hh = idx & 7;
    const unsigned short* hp = hbf + (size_t)v * DOUT + hh * 16;
    uint4 p0 = *(const uint4*)hp;
    uint4 p1 = *(const uint4*)(hp + 8);
    float hv[16];
    hv[0] = bflo(p0.x); hv[1] = bfhi(p0.x); hv[2] = bflo(p0.y); hv[3] = bfhi(p0.y);
    hv[4] = bflo(p0.z); hv[5] = bfhi(p0.z); hv[6] = bflo(p0.w); hv[7] = bfhi(p0.w);
    hv[8] = bflo(p1.x); hv[9] = bfhi(p1.x); hv[10] = bflo(p1.y); hv[11] = bfhi(p1.y);
    hv[12] = bflo(p1.z); hv[13] = bfhi(p1.z); hv[14] = bflo(p1.w); hv[15] = bfhi(p1.w);
    float s1 = 0.f, s2 = 0.f;
#pragma unroll
    for (int d = 0; d < 16; ++d) {
      s1 += hv[d] * Wa[d];
      s2 += hv[d] * Wa[16 + d];
    }
    a_src[idx] = s1;
    a_dst[idx] = s2;
    return;
  }
  // ---- fine_scatter (half-bucket = 128 nodes per block) ----
  const int b = blockIdx.x;
  const int B = b >> 1, half = b & 1;
  const int node0 = b * 128;
  if (node0 >= N) return;
  for (int i = t; i < 128 * NRANGE; i += 256) cnt[i] = 0;
  if (t == 0) lowerE = 0;
  __syncthreads();
  const int v = node0 + t;
  int r_self = -1;
  if (t < 128 && v < N) {
    r_self = rng5(v);
    cnt[t * NRANGE + r_self] = 1;  // self loop
  }
  __syncthreads();
  const int cntE = bcount[B];
  const unsigned* reg = pair_buf + B * CAP;
  for (int i = t; i < cntE; i += 256) {
    unsigned p = reg[i];
    int dl = p & 255;
    if ((dl >> 7) == half) atomicAdd(&cnt[(dl & 127) * NRANGE + rng5((int)(p >> 8))], 1);
    else if (half == 1) atomicAdd(&lowerE, 1);
  }
  redS[t] = (t < B) ? bcount[t] : 0;
  __syncthreads();
  for (int s = 128; s > 0; s >>= 1) {
    if (t < s) redS[t] += redS[t + s];
    __syncthreads();
  }
  int csr_base = redS[0] + B * 256 + (half ? (128 + lowerE) : 0);
  int tot = 0;
  if (t < 128) {
#pragma unroll
    for (int r = 0; r < NRANGE; ++r) tot += cnt[t * NRANGE + r];
  }
  int lane = t & 63, wv = t >> 6;
  int inc = wave_incl_scan(tot, lane);
  if (lane == 63) wsumS[wv] = inc;
  __syncthreads();
  int base = 0;
  for (int q = 0; q < wv; ++q) base += wsumS[q];
  int ex = base + inc - tot;
  if (t < 128 && v < N) {
    offsets[v] = csr_base + ex;
    int run = ex, rs_self = 0, c[NRANGE];
#pragma unroll
    for (int r = 0; r < NRANGE; ++r) {
      c[r] = cnt[t * NRANGE + r];
      if (r == r_self) rs_self = run;
      cur[t * NRANGE + r] = run + (r == r_self ? 1 : 0);
      run += c[r];
    }
    src_sorted[csr_base + rs_self] = (unsigned short)v;  // self loop
    uint4 L;
    L.x = (unsigned)c[0] | ((unsigned)c[1] << 16);
    L.y = (unsigned)c[2] | ((unsigned)c[3] << 16);
    L.z = (unsigned)c[4];
    L.w = 0;
    len8[v] = L;
  }
  if (b == 0 && t == 0) offsets[N] = E + N;
  __syncthreads();
  for (int i = t; i < cntE; i += 256) {
    unsigned p = reg[i];
    int dl = p & 255;
    if ((dl >> 7) == half) {
      int s = (int)(p >> 8);
      int k = atomicAdd(&cur[(dl & 127) * NRANGE + rng5(s)], 1);
      src_sorted[csr_base + k] = (unsigned short)s;
    }
  }
}

// ---------------- K4: aggregation, 4 edges / wave-instr, src-range passes ----------------
// One wave per dst node. Group g = lane>>4 handles edge j+g; sub-lane sl = lane&15
// covers cols [sl*8, sl*8+8) (16B uint4 load); head = sl>>1.
__global__ __launch_bounds__(256) void aggregate(const unsigned short* __restrict__ hbf,
                                                 const float* __restrict__ a_src,
                                                 const float* __restrict__ a_dst,
                                                 const float* __restrict__ b_att,
                                                 const int* __restrict__ offsets,
                                                 const uint4* __restrict__ len8,
                                                 const unsigned short* __restrict__ src_sorted,
                                                 float* __restrict__ out, int N) {
  int wid = blockIdx.x * 4 + (threadIdx.x >> 6);
  if (wid >= N) return;
  int lane = threadIdx.x & 63;
  int g = lane >> 4, sl = lane & 15;
  int head = sl >> 1;
  float adv = a_dst[wid * H + head] + b_att[0];
  int j = offsets[wid];
  uint4 L = len8[wid];
  int lens[NRANGE];
  lens[0] = L.x & 0xffff; lens[1] = L.x >> 16;
  lens[2] = L.y & 0xffff; lens[3] = L.y >> 16;
  lens[4] = L.z;
  float a0 = 0, a1 = 0, a2 = 0, a3 = 0, a4 = 0, a5 = 0, a6 = 0, a7 = 0, den = 0;
  for (int r = 0; r < NRANGE; ++r) {
    int end = j + lens[r];
    for (int j0 = j; j0 < end; j0 += 4) {
      int jj = j0 + g;
      bool val = jj < end;
      int jc = val ? jj : end - 1;
      int s = src_sorted[jc];
      float as = a_src[s * H + head];
      uint4 u = *(const uint4*)(hbf + s * DOUT + sl * 8);
      float e = val ? __expf(lrelu(as + adv)) : 0.f;
      den += e;
      a0 += e * bflo(u.x); a1 += e * bfhi(u.x);
      a2 += e * bflo(u.y); a3 += e * bfhi(u.y);
      a4 += e * bflo(u.z); a5 += e * bfhi(u.z);
      a6 += e * bflo(u.w); a7 += e * bfhi(u.w);
    }
    j = end;
  }
  den += __shfl_xor(den, 16, 64); den += __shfl_xor(den, 32, 64);
  a0 += __shfl_xor(a0, 16, 64); a0 += __shfl_xor(a0, 32, 64);
  a1 += __shfl_xor(a1, 16, 64); a1 += __shfl_xor(a1, 32, 64);
  a2 += __shfl_xor(a2, 16, 64); a2 += __shfl_xor(a2, 32, 64);
  a3 += __shfl_xor(a3, 16, 64); a3 += __shfl_xor(a3, 32, 64);
  a4 += __shfl_xor(a4, 16, 64); a4 += __shfl_xor(a4, 32, 64);
  a5 += __shfl_xor(a5, 16, 64); a5 += __shfl_xor(a5, 32, 64);
  a6 += __shfl_xor(a6, 16, 64); a6 += __shfl_xor(a6, 32, 64);
  a7 += __shfl_xor(a7, 16, 64); a7 += __shfl_xor(a7, 32, 64);
  float inv = 1.0f / den;
  if (g == 0) {
    float4 o = make_float4(a0 * inv, a1 * inv, a2 * inv, a3 * inv);
    *(float4*)&out[wid * DOUT + sl * 8] = o;
  } else if (g == 1) {
    float4 o = make_float4(a4 * inv, a5 * inv, a6 * inv, a7 * inv);
    *(float4*)&out[wid * DOUT + sl * 8 + 4] = o;
  }
}

extern "C" void kernel_launch(void* const* d_in, const int* in_sizes, int n_in,
                              void* d_out, int out_size, void* d_ws, size_t ws_size,
                              hipStream_t stream) {
  const float* x     = (const float*)d_in[0];
  const float* W     = (const float*)d_in[1];
  const float* Wa    = (const float*)d_in[2];
  const float* b_att = (const float*)d_in[3];
  const int*   ei    = (const int*)d_in[4];
  const int N  = in_sizes[0] / DIN;
  const int E  = in_sizes[4] / 2;
  const int NB = (N + 255) / 256;  // 196 buckets
  float* out = (float*)d_out;

  char* p = (char*)d_ws;
  auto take = [&p](size_t bytes) {
    uintptr_t u = ((uintptr_t)p + 15) & ~(uintptr_t)15;
    p = (char*)(u + bytes);
    return (void*)u;
  };
  unsigned short* hbf = (unsigned short*)take((size_t)N * DOUT * 2);
  unsigned short* Wbf = (unsigned short*)take((size_t)DOUT * DIN * 2);
  float* a_src        = (float*)take((size_t)N * H * 4);
  float* a_dst        = (float*)take((size_t)N * H * 4);
  int* bcount         = (int*)take((size_t)NB * 4);
  unsigned* pair_buf  = (unsigned*)take((size_t)NB * CAP * 4);
  int* offsets        = (int*)take((size_t)(N + 1) * 4);
  uint4* len8         = (uint4*)take((size_t)N * 16);
  unsigned short* src_sorted = (unsigned short*)take((size_t)(E + N + 16) * 2);

  dim3 b256(256);
  const int bp_blocks   = (E + CHUNK - 1) / CHUNK;   // 196
  const int gemm_blocks = (N + 31) / 32;             // 1563
  const int fs_blocks   = (N + 127) / 128;           // 391
  const int ns_blocks   = (N * H + 255) / 256;       // 1563

  conv_w<<<dim3((DOUT * DIN + 255) / 256), b256, 0, stream>>>(W, Wbf, DOUT * DIN, bcount, NB);
  bp_gemm<<<dim3(bp_blocks + gemm_blocks), b256, 0, stream>>>(
      x, Wbf, hbf, N, ei, bcount, pair_buf, E, NB, bp_blocks);
  fs_ns<<<dim3(fs_blocks + ns_blocks), b256, 0, stream>>>(
      pair_buf, bcount, offsets, len8, src_sorted, hbf, Wa, a_src, a_dst, N, E, NB, fs_blocks);
  aggregate<<<dim3((N + 3) / 4), b256, 0, stream>>>(hbf, a_src, a_dst, b_att, offsets,
                                                    len8, src_sorted, out, N);
}